// Round 2
// baseline (1753.546 us; speedup 1.0000x reference)
//
#include <hip/hip_runtime.h>
#include <math.h>

#define DIM 64
#define IN_DIM 25
#define B_GRAPHS 1024
#define STEPS 3

__device__ __forceinline__ float wave_sum(float v) {
    #pragma unroll
    for (int o = 32; o > 0; o >>= 1) v += __shfl_xor(v, o, 64);
    return v;
}

// h0 = relu(x @ lin0_W + lin0_b); also zero-init aggr (ws is poisoned 0xAA).
__global__ void lin0_kernel(const float* __restrict__ x,
                            const float* __restrict__ W,
                            const float* __restrict__ b,
                            float* __restrict__ h0,
                            float* __restrict__ aggr, int N) {
    int grp  = threadIdx.x >> 6;
    int lane = threadIdx.x & 63;
    int n = blockIdx.x * 4 + grp;
    if (n >= N) return;
    float acc = b[lane];
    const float* xr = x + (size_t)n * IN_DIM;
    #pragma unroll
    for (int k = 0; k < IN_DIM; ++k)
        acc += xr[k] * W[k * DIM + lane];
    h0[n * DIM + lane]   = fmaxf(acc, 0.f);
    aggr[n * DIM + lane] = 0.f;
}

// Per-graph starts (batch is sorted) + counts.
__global__ void bounds_kernel(const int* __restrict__ batch, int N,
                              int* __restrict__ start, int* __restrict__ count) {
    int i = blockIdx.x * blockDim.x + threadIdx.x;
    if (i >= N) return;
    int b = batch[i];
    atomicAdd(&count[b], 1);
    if (i == 0 || batch[i - 1] != b) start[b] = i;
}

// aggr[dst] += h0[src] over all edges. 16 threads/edge, float4 gather + 4 atomics.
__global__ void scatter_kernel(const int* __restrict__ ei, int E,
                               const float* __restrict__ h0,
                               float* __restrict__ aggr) {
    int t = blockIdx.x * blockDim.x + threadIdx.x;
    int e = t >> 4;
    if (e >= E) return;
    int cpart = (t & 15) * 4;
    int src = ei[e];
    int dst = ei[E + e];
    const float4 v = *reinterpret_cast<const float4*>(h0 + src * DIM + cpart);
    float* a = aggr + dst * DIM + cpart;
    atomicAdd(a + 0, v.x);
    atomicAdd(a + 1, v.y);
    atomicAdd(a + 2, v.z);
    atomicAdd(a + 3, v.w);
}

// h1 = relu((h0 + aggr) @ gin_W + gin_b), written in place over h0 (LDS-staged).
__global__ void gin_kernel(const float* __restrict__ h0,
                           const float* __restrict__ aggr,
                           const float* __restrict__ W,
                           const float* __restrict__ bias,
                           float* __restrict__ h1, int N) {
    int grp  = threadIdx.x >> 6;
    int lane = threadIdx.x & 63;
    int n = blockIdx.x * 4 + grp;
    __shared__ float s[4][DIM];
    if (n < N) s[grp][lane] = h0[n * DIM + lane] + aggr[n * DIM + lane];
    __syncthreads();
    if (n >= N) return;
    float acc = bias[lane];
    #pragma unroll 8
    for (int k = 0; k < DIM; ++k)
        acc += s[grp][k] * W[k * DIM + lane];
    h1[n * DIM + lane] = fmaxf(acc, 0.f);
}

// One block (256 thr) per graph: gates = q_star @ W_ih^T + h @ W_hh^T + b; LSTM cell.
// Writes new h into h buffer and into q_star[:, 0:64].
__global__ void lstm_kernel(const float* __restrict__ W_ih,
                            const float* __restrict__ W_hh,
                            const float* __restrict__ b_ih,
                            const float* __restrict__ b_hh,
                            float* __restrict__ q_star,
                            float* __restrict__ h,
                            float* __restrict__ c) {
    int b   = blockIdx.x;
    int tid = threadIdx.x;
    __shared__ float qs[2 * DIM];
    __shared__ float hs[DIM];
    __shared__ float gates[4 * DIM];
    if (tid < 2 * DIM)      qs[tid] = q_star[b * 2 * DIM + tid];
    else if (tid < 3 * DIM) hs[tid - 2 * DIM] = h[b * DIM + (tid - 2 * DIM)];
    __syncthreads();
    float acc = b_ih[tid] + b_hh[tid];
    const float* wi = W_ih + tid * 2 * DIM;
    #pragma unroll 8
    for (int k = 0; k < 2 * DIM; ++k) acc += qs[k] * wi[k];
    const float* wh = W_hh + tid * DIM;
    #pragma unroll 8
    for (int k = 0; k < DIM; ++k) acc += hs[k] * wh[k];
    gates[tid] = acc;
    __syncthreads();
    if (tid < DIM) {
        float ig = gates[tid];
        float fg = gates[DIM + tid];
        float gg = gates[2 * DIM + tid];
        float og = gates[3 * DIM + tid];
        float si = 1.f / (1.f + expf(-ig));
        float sf = 1.f / (1.f + expf(-fg));
        float so = 1.f / (1.f + expf(-og));
        float cn = sf * c[b * DIM + tid] + si * tanhf(gg);
        float hn = so * tanhf(cn);
        c[b * DIM + tid] = cn;
        h[b * DIM + tid] = hn;
        q_star[b * 2 * DIM + tid] = hn;
    }
}

// One block (256 thr = 4 waves) per graph: softmax attention over its node range.
__global__ void att_kernel(const float* __restrict__ h1,
                           const float* __restrict__ hq,
                           const int* __restrict__ start,
                           const int* __restrict__ count,
                           float* __restrict__ q_star) {
    int b    = blockIdx.x;
    int lane = threadIdx.x & 63;
    int grp  = threadIdx.x >> 6;
    __shared__ float q[DIM];
    __shared__ float smax[4];
    __shared__ float sden[4];
    __shared__ float sr[4][DIM];
    if (threadIdx.x < DIM) q[threadIdx.x] = hq[b * DIM + threadIdx.x];
    int st = start[b], cnt = count[b];
    __syncthreads();
    float qv = q[lane];

    float gmax = -INFINITY;
    for (int i = grp; i < cnt; i += 4) {
        int n = st + i;
        float e = wave_sum(h1[n * DIM + lane] * qv);
        gmax = fmaxf(gmax, e);
    }
    if (lane == 0) smax[grp] = gmax;
    __syncthreads();
    float m = fmaxf(fmaxf(smax[0], smax[1]), fmaxf(smax[2], smax[3]));

    float den = 0.f, r = 0.f;
    for (int i = grp; i < cnt; i += 4) {
        int n = st + i;
        float v = h1[n * DIM + lane];
        float e = wave_sum(v * qv);
        float w = expf(e - m);
        den += w;
        r   += w * v;
    }
    if (lane == 0) sden[grp] = den;
    sr[grp][lane] = r;
    __syncthreads();
    if (grp == 0) {
        float rt = sr[0][lane] + sr[1][lane] + sr[2][lane] + sr[3][lane];
        float dt = sden[0] + sden[1] + sden[2] + sden[3];
        if (dt == 0.f) dt = 1.f;
        q_star[b * 2 * DIM + DIM + lane] = rt / dt;
    }
}

// out[b] = relu(q_star @ lin1_W + lin1_b) @ lin2_W + lin2_b. One wave per graph.
__global__ void head_kernel(const float* __restrict__ q_star,
                            const float* __restrict__ lin1_W,
                            const float* __restrict__ lin1_b,
                            const float* __restrict__ lin2_W,
                            const float* __restrict__ lin2_b,
                            float* __restrict__ out) {
    int b = blockIdx.x;
    int d = threadIdx.x;  // block of 64
    __shared__ float qs[2 * DIM];
    qs[d]       = q_star[b * 2 * DIM + d];
    qs[DIM + d] = q_star[b * 2 * DIM + DIM + d];
    __syncthreads();
    float acc = lin1_b[d];
    #pragma unroll 8
    for (int k = 0; k < 2 * DIM; ++k) acc += qs[k] * lin1_W[k * DIM + d];
    acc = fmaxf(acc, 0.f);
    float v = acc * lin2_W[d];
    v = wave_sum(v);
    if (d == 0) out[b] = v + lin2_b[0];
}

extern "C" void kernel_launch(void* const* d_in, const int* in_sizes, int n_in,
                              void* d_out, int out_size, void* d_ws, size_t ws_size,
                              hipStream_t stream) {
    const float* x      = (const float*)d_in[0];
    const int*   ei     = (const int*)d_in[1];
    const int*   batch  = (const int*)d_in[2];
    const float* lin0_W = (const float*)d_in[3];
    const float* lin0_b = (const float*)d_in[4];
    const float* gin_W  = (const float*)d_in[5];
    const float* gin_b  = (const float*)d_in[6];
    const float* W_ih   = (const float*)d_in[7];
    const float* W_hh   = (const float*)d_in[8];
    const float* b_ih   = (const float*)d_in[9];
    const float* b_hh   = (const float*)d_in[10];
    const float* lin1_W = (const float*)d_in[11];
    const float* lin1_b = (const float*)d_in[12];
    const float* lin2_W = (const float*)d_in[13];
    const float* lin2_b = (const float*)d_in[14];
    float* out = (float*)d_out;

    const int N = in_sizes[2];        // 100000 nodes (batch vector length)
    const int E = in_sizes[1] / 2;    // 1600000 edges

    char* ws = (char*)d_ws;
    size_t off = 0;
    auto take = [&](size_t bytes) -> char* {
        char* p = ws + off;
        off += (bytes + 255) & ~(size_t)255;
        return p;
    };
    float* h0     = (float*)take((size_t)N * DIM * 4);              // reused as h1
    float* aggr   = (float*)take((size_t)N * DIM * 4);
    float* q_star = (float*)take((size_t)B_GRAPHS * 2 * DIM * 4);   // contiguous with
    float* hbuf   = (float*)take((size_t)B_GRAPHS * DIM * 4);       // hbuf, cbuf, count
    float* cbuf   = (float*)take((size_t)B_GRAPHS * DIM * 4);       // (all 256B multiples)
    int*   count  = (int*)take((size_t)B_GRAPHS * 4);
    int*   startb = (int*)take((size_t)B_GRAPHS * 4);

    // Zero q_star, h, c, count in one contiguous memset (ws is poisoned each call).
    size_t zero_bytes = (size_t)B_GRAPHS * (2 * DIM + DIM + DIM) * 4 + (size_t)B_GRAPHS * 4;
    hipMemsetAsync(q_star, 0, zero_bytes, stream);

    int nb4 = (N + 3) / 4;
    hipLaunchKernelGGL(lin0_kernel, dim3(nb4), dim3(256), 0, stream,
                       x, lin0_W, lin0_b, h0, aggr, N);
    hipLaunchKernelGGL(bounds_kernel, dim3((N + 255) / 256), dim3(256), 0, stream,
                       batch, N, startb, count);
    hipLaunchKernelGGL(scatter_kernel, dim3((E * 16 + 255) / 256), dim3(256), 0, stream,
                       ei, E, h0, aggr);
    hipLaunchKernelGGL(gin_kernel, dim3(nb4), dim3(256), 0, stream,
                       h0, aggr, gin_W, gin_b, h0, N);
    for (int s = 0; s < STEPS; ++s) {
        hipLaunchKernelGGL(lstm_kernel, dim3(B_GRAPHS), dim3(256), 0, stream,
                           W_ih, W_hh, b_ih, b_hh, q_star, hbuf, cbuf);
        hipLaunchKernelGGL(att_kernel, dim3(B_GRAPHS), dim3(256), 0, stream,
                           h0, hbuf, startb, count, q_star);
    }
    hipLaunchKernelGGL(head_kernel, dim3(B_GRAPHS), dim3(64), 0, stream,
                       q_star, lin1_W, lin1_b, lin2_W, lin2_b, out);
}

// Round 3
// 668.785 us; speedup vs baseline: 2.6220x; 2.6220x over previous
//
#include <hip/hip_runtime.h>
#include <math.h>

#define DIM 64
#define IN_DIM 25
#define B_GRAPHS 1024
#define STEPS 3

__device__ __forceinline__ float wave_sum(float v) {
    #pragma unroll
    for (int o = 32; o > 0; o >>= 1) v += __shfl_xor(v, o, 64);
    return v;
}

// h0 = relu(x @ lin0_W + lin0_b). 4 nodes/block, lane = out channel.
__global__ void lin0_kernel(const float* __restrict__ x,
                            const float* __restrict__ W,
                            const float* __restrict__ b,
                            float* __restrict__ h0, int N) {
    int grp  = threadIdx.x >> 6;
    int lane = threadIdx.x & 63;
    int n = blockIdx.x * 4 + grp;
    if (n >= N) return;
    float acc = b[lane];
    const float* xr = x + (size_t)n * IN_DIM;
    #pragma unroll
    for (int k = 0; k < IN_DIM; ++k)
        acc += xr[k] * W[k * DIM + lane];
    h0[n * DIM + lane] = fmaxf(acc, 0.f);
}

// Per-graph starts (batch is sorted) + counts.
__global__ void bounds_kernel(const int* __restrict__ batch, int N,
                              int* __restrict__ start, int* __restrict__ count) {
    int i = blockIdx.x * blockDim.x + threadIdx.x;
    if (i >= N) return;
    int b = batch[i];
    atomicAdd(&count[b], 1);
    if (i == 0 || batch[i - 1] != b) start[b] = i;
}

// In-degree histogram over edge destinations.
__global__ void deg_kernel(const int* __restrict__ ei, int E, int* __restrict__ deg) {
    int e = blockIdx.x * blockDim.x + threadIdx.x;
    if (e >= E) return;
    atomicAdd(&deg[ei[E + e]], 1);
}

// Block-level exclusive scan of deg -> rowptr; per-block totals -> bsum.
__global__ void scan_blocks(const int* __restrict__ deg, int N,
                            int* __restrict__ rowptr, int* __restrict__ bsum) {
    __shared__ int s[256];
    int i = blockIdx.x * 256 + threadIdx.x;
    int v = (i < N) ? deg[i] : 0;
    s[threadIdx.x] = v;
    __syncthreads();
    for (int o = 1; o < 256; o <<= 1) {
        int t = (threadIdx.x >= o) ? s[threadIdx.x - o] : 0;
        __syncthreads();
        s[threadIdx.x] += t;
        __syncthreads();
    }
    if (i < N) rowptr[i] = s[threadIdx.x] - v;   // exclusive
    if (threadIdx.x == 255) bsum[blockIdx.x] = s[255];
}

// Exclusive scan of the (<512) block totals, in place.
__global__ void scan_top(int* __restrict__ bsum, int nb) {
    __shared__ int s[512];
    int v = (threadIdx.x < nb) ? bsum[threadIdx.x] : 0;
    s[threadIdx.x] = v;
    __syncthreads();
    for (int o = 1; o < 512; o <<= 1) {
        int t = (threadIdx.x >= o) ? s[threadIdx.x - o] : 0;
        __syncthreads();
        s[threadIdx.x] += t;
        __syncthreads();
    }
    if (threadIdx.x < nb) bsum[threadIdx.x] = s[threadIdx.x] - v;
}

__global__ void scan_add(int* __restrict__ rowptr, const int* __restrict__ bsum, int N) {
    int i = blockIdx.x * 256 + threadIdx.x;
    if (i < N) rowptr[i] += bsum[blockIdx.x];
}

// Fill CSR: csr[pos++] = src per dst. rowptr becomes INCLUSIVE prefix afterwards.
__global__ void fill_csr(const int* __restrict__ ei, int E,
                         int* __restrict__ rowptr, int* __restrict__ csr) {
    int e = blockIdx.x * blockDim.x + threadIdx.x;
    if (e >= E) return;
    int src = ei[e];
    int dst = ei[E + e];
    int pos = atomicAdd(&rowptr[dst], 1);
    csr[pos] = src;
}

// Fused neighbor-sum + GIN matmul: h1 = relu((h0[n] + sum_src h0[src]) @ W + b).
// One wave per node (lane = channel); csr indices loaded 64-wide, shfl-broadcast.
__global__ void gin_gather_kernel(const float* __restrict__ h0,
                                  const int* __restrict__ rowptr,  // inclusive after fill
                                  const int* __restrict__ deg,
                                  const int* __restrict__ csr,
                                  const float* __restrict__ W,
                                  const float* __restrict__ bias,
                                  float* __restrict__ h1, int N) {
    int grp  = threadIdx.x >> 6;
    int lane = threadIdx.x & 63;
    int n = blockIdx.x * 4 + grp;
    __shared__ float s[4][DIM];
    if (n < N) {
        float acc = h0[(size_t)n * DIM + lane];
        int end = rowptr[n];
        int d   = deg[n];
        for (int base = end - d; base < end; base += 64) {
            int idx = (base + lane < end) ? csr[base + lane] : 0;
            int m = end - base; if (m > 64) m = 64;
            for (int j = 0; j < m; ++j) {
                int src = __shfl(idx, j, 64);
                acc += h0[(size_t)src * DIM + lane];
            }
        }
        s[grp][lane] = acc;
    }
    __syncthreads();
    if (n >= N) return;
    float a2 = bias[lane];
    #pragma unroll 8
    for (int k = 0; k < DIM; ++k)
        a2 += s[grp][k] * W[k * DIM + lane];
    h1[(size_t)n * DIM + lane] = fmaxf(a2, 0.f);
}

// One block (256 thr) per graph: gates = q_star @ W_ih^T + h @ W_hh^T + b; LSTM cell.
__global__ void lstm_kernel(const float* __restrict__ W_ih,
                            const float* __restrict__ W_hh,
                            const float* __restrict__ b_ih,
                            const float* __restrict__ b_hh,
                            float* __restrict__ q_star,
                            float* __restrict__ h,
                            float* __restrict__ c) {
    int b   = blockIdx.x;
    int tid = threadIdx.x;
    __shared__ float qs[2 * DIM];
    __shared__ float hs[DIM];
    __shared__ float gates[4 * DIM];
    if (tid < 2 * DIM)      qs[tid] = q_star[b * 2 * DIM + tid];
    else if (tid < 3 * DIM) hs[tid - 2 * DIM] = h[b * DIM + (tid - 2 * DIM)];
    __syncthreads();
    float acc = b_ih[tid] + b_hh[tid];
    const float* wi = W_ih + tid * 2 * DIM;
    #pragma unroll 8
    for (int k = 0; k < 2 * DIM; ++k) acc += qs[k] * wi[k];
    const float* wh = W_hh + tid * DIM;
    #pragma unroll 8
    for (int k = 0; k < DIM; ++k) acc += hs[k] * wh[k];
    gates[tid] = acc;
    __syncthreads();
    if (tid < DIM) {
        float ig = gates[tid];
        float fg = gates[DIM + tid];
        float gg = gates[2 * DIM + tid];
        float og = gates[3 * DIM + tid];
        float si = 1.f / (1.f + expf(-ig));
        float sf = 1.f / (1.f + expf(-fg));
        float so = 1.f / (1.f + expf(-og));
        float cn = sf * c[b * DIM + tid] + si * tanhf(gg);
        float hn = so * tanhf(cn);
        c[b * DIM + tid] = cn;
        h[b * DIM + tid] = hn;
        q_star[b * 2 * DIM + tid] = hn;
    }
}

// One block (256 thr = 4 waves) per graph: softmax attention over its node range.
__global__ void att_kernel(const float* __restrict__ h1,
                           const float* __restrict__ hq,
                           const int* __restrict__ start,
                           const int* __restrict__ count,
                           float* __restrict__ q_star) {
    int b    = blockIdx.x;
    int lane = threadIdx.x & 63;
    int grp  = threadIdx.x >> 6;
    __shared__ float q[DIM];
    __shared__ float smax[4];
    __shared__ float sden[4];
    __shared__ float sr[4][DIM];
    if (threadIdx.x < DIM) q[threadIdx.x] = hq[b * DIM + threadIdx.x];
    int st = start[b], cnt = count[b];
    __syncthreads();
    float qv = q[lane];

    float gmax = -INFINITY;
    for (int i = grp; i < cnt; i += 4) {
        int n = st + i;
        float e = wave_sum(h1[(size_t)n * DIM + lane] * qv);
        gmax = fmaxf(gmax, e);
    }
    if (lane == 0) smax[grp] = gmax;
    __syncthreads();
    float m = fmaxf(fmaxf(smax[0], smax[1]), fmaxf(smax[2], smax[3]));

    float den = 0.f, r = 0.f;
    for (int i = grp; i < cnt; i += 4) {
        int n = st + i;
        float v = h1[(size_t)n * DIM + lane];
        float e = wave_sum(v * qv);
        float w = expf(e - m);
        den += w;
        r   += w * v;
    }
    if (lane == 0) sden[grp] = den;
    sr[grp][lane] = r;
    __syncthreads();
    if (grp == 0) {
        float rt = sr[0][lane] + sr[1][lane] + sr[2][lane] + sr[3][lane];
        float dt = sden[0] + sden[1] + sden[2] + sden[3];
        if (dt == 0.f) dt = 1.f;
        q_star[b * 2 * DIM + DIM + lane] = rt / dt;
    }
}

// out[b] = relu(q_star @ lin1_W + lin1_b) @ lin2_W + lin2_b. One wave per graph.
__global__ void head_kernel(const float* __restrict__ q_star,
                            const float* __restrict__ lin1_W,
                            const float* __restrict__ lin1_b,
                            const float* __restrict__ lin2_W,
                            const float* __restrict__ lin2_b,
                            float* __restrict__ out) {
    int b = blockIdx.x;
    int d = threadIdx.x;  // block of 64
    __shared__ float qs[2 * DIM];
    qs[d]       = q_star[b * 2 * DIM + d];
    qs[DIM + d] = q_star[b * 2 * DIM + DIM + d];
    __syncthreads();
    float acc = lin1_b[d];
    #pragma unroll 8
    for (int k = 0; k < 2 * DIM; ++k) acc += qs[k] * lin1_W[k * DIM + d];
    acc = fmaxf(acc, 0.f);
    float v = acc * lin2_W[d];
    v = wave_sum(v);
    if (d == 0) out[b] = v + lin2_b[0];
}

extern "C" void kernel_launch(void* const* d_in, const int* in_sizes, int n_in,
                              void* d_out, int out_size, void* d_ws, size_t ws_size,
                              hipStream_t stream) {
    const float* x      = (const float*)d_in[0];
    const int*   ei     = (const int*)d_in[1];
    const int*   batch  = (const int*)d_in[2];
    const float* lin0_W = (const float*)d_in[3];
    const float* lin0_b = (const float*)d_in[4];
    const float* gin_W  = (const float*)d_in[5];
    const float* gin_b  = (const float*)d_in[6];
    const float* W_ih   = (const float*)d_in[7];
    const float* W_hh   = (const float*)d_in[8];
    const float* b_ih   = (const float*)d_in[9];
    const float* b_hh   = (const float*)d_in[10];
    const float* lin1_W = (const float*)d_in[11];
    const float* lin1_b = (const float*)d_in[12];
    const float* lin2_W = (const float*)d_in[13];
    const float* lin2_b = (const float*)d_in[14];
    float* out = (float*)d_out;

    const int N = in_sizes[2];        // 100000 nodes
    const int E = in_sizes[1] / 2;    // 1600000 edges

    char* ws = (char*)d_ws;
    size_t off = 0;
    auto take = [&](size_t bytes) -> char* {
        char* p = ws + off;
        off += (bytes + 255) & ~(size_t)255;
        return p;
    };
    float* h0     = (float*)take((size_t)N * DIM * 4);
    float* h1     = (float*)take((size_t)N * DIM * 4);
    // ---- zeroed region start (one contiguous memset) ----
    float* q_star = (float*)take((size_t)B_GRAPHS * 2 * DIM * 4);
    float* hbuf   = (float*)take((size_t)B_GRAPHS * DIM * 4);
    float* cbuf   = (float*)take((size_t)B_GRAPHS * DIM * 4);
    int*   count  = (int*)take((size_t)B_GRAPHS * 4);
    int*   deg    = (int*)take((size_t)N * 4);
    // ---- zeroed region end ----
    int*   startb = (int*)take((size_t)B_GRAPHS * 4);
    int*   rowptr = (int*)take((size_t)N * 4);
    int*   bsum   = (int*)take((size_t)512 * 4);
    int*   csr    = (int*)take((size_t)E * 4);

    size_t zero_bytes = (size_t)((char*)startb - (char*)q_star);
    hipMemsetAsync(q_star, 0, zero_bytes, stream);

    int nb4   = (N + 3) / 4;
    int nb256 = (N + 255) / 256;
    int eb256 = (E + 255) / 256;

    hipLaunchKernelGGL(lin0_kernel, dim3(nb4), dim3(256), 0, stream,
                       x, lin0_W, lin0_b, h0, N);
    hipLaunchKernelGGL(bounds_kernel, dim3(nb256), dim3(256), 0, stream,
                       batch, N, startb, count);
    hipLaunchKernelGGL(deg_kernel, dim3(eb256), dim3(256), 0, stream, ei, E, deg);
    hipLaunchKernelGGL(scan_blocks, dim3(nb256), dim3(256), 0, stream,
                       deg, N, rowptr, bsum);
    hipLaunchKernelGGL(scan_top, dim3(1), dim3(512), 0, stream, bsum, nb256);
    hipLaunchKernelGGL(scan_add, dim3(nb256), dim3(256), 0, stream, rowptr, bsum, N);
    hipLaunchKernelGGL(fill_csr, dim3(eb256), dim3(256), 0, stream, ei, E, rowptr, csr);
    hipLaunchKernelGGL(gin_gather_kernel, dim3(nb4), dim3(256), 0, stream,
                       h0, rowptr, deg, csr, gin_W, gin_b, h1, N);
    for (int s = 0; s < STEPS; ++s) {
        hipLaunchKernelGGL(lstm_kernel, dim3(B_GRAPHS), dim3(256), 0, stream,
                           W_ih, W_hh, b_ih, b_hh, q_star, hbuf, cbuf);
        hipLaunchKernelGGL(att_kernel, dim3(B_GRAPHS), dim3(256), 0, stream,
                           h1, hbuf, startb, count, q_star);
    }
    hipLaunchKernelGGL(head_kernel, dim3(B_GRAPHS), dim3(64), 0, stream,
                       q_star, lin1_W, lin1_b, lin2_W, lin2_b, out);
}

// Round 4
// 566.512 us; speedup vs baseline: 3.0953x; 1.1805x over previous
//
#include <hip/hip_runtime.h>
#include <math.h>

#define DIM 64
#define IN_DIM 25
#define B_GRAPHS 1024
#define STEPS 3

__device__ __forceinline__ float wave_sum(float v) {
    #pragma unroll
    for (int o = 32; o > 0; o >>= 1) v += __shfl_xor(v, o, 64);
    return v;
}

// h0 = relu(x @ lin0_W + lin0_b). 4 nodes/block, lane = out channel.
__global__ void lin0_kernel(const float* __restrict__ x,
                            const float* __restrict__ W,
                            const float* __restrict__ b,
                            float* __restrict__ h0, int N) {
    int grp  = threadIdx.x >> 6;
    int lane = threadIdx.x & 63;
    int n = blockIdx.x * 4 + grp;
    if (n >= N) return;
    float acc = b[lane];
    const float* xr = x + (size_t)n * IN_DIM;
    #pragma unroll
    for (int k = 0; k < IN_DIM; ++k)
        acc += xr[k] * W[k * DIM + lane];
    h0[n * DIM + lane] = fmaxf(acc, 0.f);
}

// Combined: in-degree histogram (E threads) + per-graph start/count (N threads).
__global__ void hist_kernel(const int* __restrict__ ei, int E,
                            const int* __restrict__ batch, int N,
                            int* __restrict__ deg,
                            int* __restrict__ start, int* __restrict__ count) {
    int i = blockIdx.x * blockDim.x + threadIdx.x;
    if (i < E) atomicAdd(&deg[ei[E + i]], 1);
    if (i < N) {
        int b = batch[i];
        atomicAdd(&count[b], 1);
        if (i == 0 || batch[i - 1] != b) start[b] = i;
    }
}

// Block-level exclusive scan of deg -> rowptr; per-block totals -> bsum.
__global__ void scan_blocks(const int* __restrict__ deg, int N,
                            int* __restrict__ rowptr, int* __restrict__ bsum) {
    __shared__ int s[256];
    int i = blockIdx.x * 256 + threadIdx.x;
    int v = (i < N) ? deg[i] : 0;
    s[threadIdx.x] = v;
    __syncthreads();
    for (int o = 1; o < 256; o <<= 1) {
        int t = (threadIdx.x >= o) ? s[threadIdx.x - o] : 0;
        __syncthreads();
        s[threadIdx.x] += t;
        __syncthreads();
    }
    if (i < N) rowptr[i] = s[threadIdx.x] - v;   // exclusive
    if (threadIdx.x == 255) bsum[blockIdx.x] = s[255];
}

// Exclusive scan of the (<512) block totals, in place.
__global__ void scan_top(int* __restrict__ bsum, int nb) {
    __shared__ int s[512];
    int v = (threadIdx.x < nb) ? bsum[threadIdx.x] : 0;
    s[threadIdx.x] = v;
    __syncthreads();
    for (int o = 1; o < 512; o <<= 1) {
        int t = (threadIdx.x >= o) ? s[threadIdx.x - o] : 0;
        __syncthreads();
        s[threadIdx.x] += t;
        __syncthreads();
    }
    if (threadIdx.x < nb) bsum[threadIdx.x] = s[threadIdx.x] - v;
}

__global__ void scan_add(int* __restrict__ rowptr, const int* __restrict__ bsum, int N) {
    int i = blockIdx.x * 256 + threadIdx.x;
    if (i < N) rowptr[i] += bsum[blockIdx.x];
}

// Fill CSR: csr[pos++] = src per dst. rowptr becomes INCLUSIVE prefix afterwards.
__global__ void fill_csr(const int* __restrict__ ei, int E,
                         int* __restrict__ rowptr, int* __restrict__ csr) {
    int e = blockIdx.x * blockDim.x + threadIdx.x;
    if (e >= E) return;
    int src = ei[e];
    int dst = ei[E + e];
    int pos = atomicAdd(&rowptr[dst], 1);
    csr[pos] = src;
}

// Fused neighbor-sum + GIN matmul. One wave per node (lane = channel).
// 8-way unrolled gather -> 8 outstanding loads per wave (MLP fix: VGPR was 12).
__global__ void gin_gather_kernel(const float* __restrict__ h0,
                                  const int* __restrict__ rowptr,  // inclusive
                                  const int* __restrict__ deg,
                                  const int* __restrict__ csr,
                                  const float* __restrict__ W,
                                  const float* __restrict__ bias,
                                  float* __restrict__ h1, int N) {
    int grp  = threadIdx.x >> 6;
    int lane = threadIdx.x & 63;
    int n = blockIdx.x * 4 + grp;
    __shared__ float s[4][DIM];
    if (n < N) {
        float a0 = h0[(size_t)n * DIM + lane];
        float a1 = 0.f, a2 = 0.f, a3 = 0.f, a4 = 0.f, a5 = 0.f, a6 = 0.f, a7 = 0.f;
        int end = rowptr[n];
        int d   = deg[n];
        for (int base = end - d; base < end; base += 64) {
            int idx = (base + lane < end) ? csr[base + lane] : 0;
            int m = end - base; if (m > 64) m = 64;
            int j = 0;
            for (; j + 8 <= m; j += 8) {
                int s0 = __shfl(idx, j + 0, 64);
                int s1 = __shfl(idx, j + 1, 64);
                int s2 = __shfl(idx, j + 2, 64);
                int s3 = __shfl(idx, j + 3, 64);
                int s4 = __shfl(idx, j + 4, 64);
                int s5 = __shfl(idx, j + 5, 64);
                int s6 = __shfl(idx, j + 6, 64);
                int s7 = __shfl(idx, j + 7, 64);
                float v0 = h0[(size_t)s0 * DIM + lane];
                float v1 = h0[(size_t)s1 * DIM + lane];
                float v2 = h0[(size_t)s2 * DIM + lane];
                float v3 = h0[(size_t)s3 * DIM + lane];
                float v4 = h0[(size_t)s4 * DIM + lane];
                float v5 = h0[(size_t)s5 * DIM + lane];
                float v6 = h0[(size_t)s6 * DIM + lane];
                float v7 = h0[(size_t)s7 * DIM + lane];
                a0 += v0; a1 += v1; a2 += v2; a3 += v3;
                a4 += v4; a5 += v5; a6 += v6; a7 += v7;
            }
            for (; j < m; ++j) {
                int sj = __shfl(idx, j, 64);
                a0 += h0[(size_t)sj * DIM + lane];
            }
        }
        s[grp][lane] = ((a0 + a1) + (a2 + a3)) + ((a4 + a5) + (a6 + a7));
    }
    __syncthreads();
    if (n >= N) return;
    float acc = bias[lane];
    #pragma unroll 8
    for (int k = 0; k < DIM; ++k)
        acc += s[grp][k] * W[k * DIM + lane];
    h1[(size_t)n * DIM + lane] = fmaxf(acc, 0.f);
}

// One block (256 thr) per graph: LSTM cell + softmax attention, fused.
// Attention layout: 4 nodes/wave, 16 lanes/node, float4 loads (channels 4*sub..+3).
__global__ void set2set_step_kernel(const float* __restrict__ h1,
                                    const float* __restrict__ W_ih,
                                    const float* __restrict__ W_hh,
                                    const float* __restrict__ b_ih,
                                    const float* __restrict__ b_hh,
                                    const int* __restrict__ start,
                                    const int* __restrict__ count,
                                    float* __restrict__ q_star,
                                    float* __restrict__ h,
                                    float* __restrict__ c) {
    int b   = blockIdx.x;
    int tid = threadIdx.x;
    __shared__ __align__(16) float qs[2 * DIM];
    __shared__ __align__(16) float hs[DIM];
    __shared__ __align__(16) float q[DIM];
    __shared__ float gates[4 * DIM];
    __shared__ float smax[4];
    __shared__ float sden[16];
    __shared__ __align__(16) float4 sr[16][16];   // [grp*4+jslot][sub]

    // ---- LSTM ----
    if (tid < 2 * DIM)      qs[tid] = q_star[b * 2 * DIM + tid];
    else if (tid < 3 * DIM) hs[tid - 2 * DIM] = h[b * DIM + (tid - 2 * DIM)];
    __syncthreads();
    {
        float acc = b_ih[tid] + b_hh[tid];
        const float4* wi4 = (const float4*)(W_ih + (size_t)tid * 2 * DIM);
        const float4* qs4 = (const float4*)qs;
        #pragma unroll
        for (int k = 0; k < 2 * DIM / 4; ++k) {
            float4 w = wi4[k], v = qs4[k];
            acc += w.x * v.x + w.y * v.y + w.z * v.z + w.w * v.w;
        }
        const float4* wh4 = (const float4*)(W_hh + (size_t)tid * DIM);
        const float4* hs4 = (const float4*)hs;
        #pragma unroll
        for (int k = 0; k < DIM / 4; ++k) {
            float4 w = wh4[k], v = hs4[k];
            acc += w.x * v.x + w.y * v.y + w.z * v.z + w.w * v.w;
        }
        gates[tid] = acc;
    }
    __syncthreads();
    if (tid < DIM) {
        float ig = gates[tid];
        float fg = gates[DIM + tid];
        float gg = gates[2 * DIM + tid];
        float og = gates[3 * DIM + tid];
        float si = 1.f / (1.f + __expf(-ig));
        float sf = 1.f / (1.f + __expf(-fg));
        float so = 1.f / (1.f + __expf(-og));
        float cn = sf * c[b * DIM + tid] + si * tanhf(gg);
        float hn = so * tanhf(cn);
        c[b * DIM + tid] = cn;
        h[b * DIM + tid] = hn;
        q_star[b * 2 * DIM + tid] = hn;
        q[tid] = hn;
    }
    __syncthreads();

    // ---- attention ----
    int lane  = tid & 63;
    int grp   = tid >> 6;
    int sub   = lane & 15;     // channel group: channels 4*sub .. 4*sub+3
    int jslot = lane >> 4;     // node slot within wave
    int st = start[b], cnt = count[b];
    const float4 q4 = *(const float4*)(&q[4 * sub]);

    float gmax = -INFINITY;
    for (int i = grp * 4 + jslot; i < cnt; i += 16) {
        const float4 v = *(const float4*)(h1 + (size_t)(st + i) * DIM + 4 * sub);
        float p = v.x * q4.x + v.y * q4.y + v.z * q4.z + v.w * q4.w;
        p += __shfl_xor(p, 1, 64);
        p += __shfl_xor(p, 2, 64);
        p += __shfl_xor(p, 4, 64);
        p += __shfl_xor(p, 8, 64);
        gmax = fmaxf(gmax, p);
    }
    gmax = fmaxf(gmax, __shfl_xor(gmax, 16, 64));
    gmax = fmaxf(gmax, __shfl_xor(gmax, 32, 64));
    if (lane == 0) smax[grp] = gmax;
    __syncthreads();
    float m = fmaxf(fmaxf(smax[0], smax[1]), fmaxf(smax[2], smax[3]));

    float4 racc = {0.f, 0.f, 0.f, 0.f};
    float den = 0.f;
    for (int i = grp * 4 + jslot; i < cnt; i += 16) {
        const float4 v = *(const float4*)(h1 + (size_t)(st + i) * DIM + 4 * sub);
        float p = v.x * q4.x + v.y * q4.y + v.z * q4.z + v.w * q4.w;
        p += __shfl_xor(p, 1, 64);
        p += __shfl_xor(p, 2, 64);
        p += __shfl_xor(p, 4, 64);
        p += __shfl_xor(p, 8, 64);
        float w = __expf(p - m);
        if (sub == 0) den += w;
        racc.x += w * v.x; racc.y += w * v.y; racc.z += w * v.z; racc.w += w * v.w;
    }
    sr[grp * 4 + jslot][sub] = racc;
    if (sub == 0) sden[grp * 4 + jslot] = den;
    __syncthreads();
    if (tid < DIM) {
        float tot = 0.f;
        #pragma unroll
        for (int row = 0; row < 16; ++row) {
            const float* base = (const float*)&sr[row][tid >> 2];
            tot += base[tid & 3];
        }
        float dt = 0.f;
        #pragma unroll
        for (int row = 0; row < 16; ++row) dt += sden[row];
        if (dt == 0.f) dt = 1.f;
        q_star[b * 2 * DIM + DIM + tid] = tot / dt;
    }
}

// out[b] = relu(q_star @ lin1_W + lin1_b) @ lin2_W + lin2_b. One wave per graph.
__global__ void head_kernel(const float* __restrict__ q_star,
                            const float* __restrict__ lin1_W,
                            const float* __restrict__ lin1_b,
                            const float* __restrict__ lin2_W,
                            const float* __restrict__ lin2_b,
                            float* __restrict__ out) {
    int b = blockIdx.x;
    int d = threadIdx.x;  // block of 64
    __shared__ float qs[2 * DIM];
    qs[d]       = q_star[b * 2 * DIM + d];
    qs[DIM + d] = q_star[b * 2 * DIM + DIM + d];
    __syncthreads();
    float acc = lin1_b[d];
    #pragma unroll 8
    for (int k = 0; k < 2 * DIM; ++k) acc += qs[k] * lin1_W[k * DIM + d];
    acc = fmaxf(acc, 0.f);
    float v = acc * lin2_W[d];
    v = wave_sum(v);
    if (d == 0) out[b] = v + lin2_b[0];
}

extern "C" void kernel_launch(void* const* d_in, const int* in_sizes, int n_in,
                              void* d_out, int out_size, void* d_ws, size_t ws_size,
                              hipStream_t stream) {
    const float* x      = (const float*)d_in[0];
    const int*   ei     = (const int*)d_in[1];
    const int*   batch  = (const int*)d_in[2];
    const float* lin0_W = (const float*)d_in[3];
    const float* lin0_b = (const float*)d_in[4];
    const float* gin_W  = (const float*)d_in[5];
    const float* gin_b  = (const float*)d_in[6];
    const float* W_ih   = (const float*)d_in[7];
    const float* W_hh   = (const float*)d_in[8];
    const float* b_ih   = (const float*)d_in[9];
    const float* b_hh   = (const float*)d_in[10];
    const float* lin1_W = (const float*)d_in[11];
    const float* lin1_b = (const float*)d_in[12];
    const float* lin2_W = (const float*)d_in[13];
    const float* lin2_b = (const float*)d_in[14];
    float* out = (float*)d_out;

    const int N = in_sizes[2];        // 100000 nodes
    const int E = in_sizes[1] / 2;    // 1600000 edges

    char* ws = (char*)d_ws;
    size_t off = 0;
    auto take = [&](size_t bytes) -> char* {
        char* p = ws + off;
        off += (bytes + 255) & ~(size_t)255;
        return p;
    };
    float* h0     = (float*)take((size_t)N * DIM * 4);
    float* h1     = (float*)take((size_t)N * DIM * 4);
    // ---- zeroed region start (one contiguous memset) ----
    float* q_star = (float*)take((size_t)B_GRAPHS * 2 * DIM * 4);
    float* hbuf   = (float*)take((size_t)B_GRAPHS * DIM * 4);
    float* cbuf   = (float*)take((size_t)B_GRAPHS * DIM * 4);
    int*   count  = (int*)take((size_t)B_GRAPHS * 4);
    int*   deg    = (int*)take((size_t)N * 4);
    // ---- zeroed region end ----
    int*   startb = (int*)take((size_t)B_GRAPHS * 4);
    int*   rowptr = (int*)take((size_t)N * 4);
    int*   bsum   = (int*)take((size_t)512 * 4);
    int*   csr    = (int*)take((size_t)E * 4);

    size_t zero_bytes = (size_t)((char*)startb - (char*)q_star);
    hipMemsetAsync(q_star, 0, zero_bytes, stream);

    int nb4   = (N + 3) / 4;
    int nb256 = (N + 255) / 256;
    int eb256 = (E + 255) / 256;

    hipLaunchKernelGGL(lin0_kernel, dim3(nb4), dim3(256), 0, stream,
                       x, lin0_W, lin0_b, h0, N);
    hipLaunchKernelGGL(hist_kernel, dim3(eb256), dim3(256), 0, stream,
                       ei, E, batch, N, deg, startb, count);
    hipLaunchKernelGGL(scan_blocks, dim3(nb256), dim3(256), 0, stream,
                       deg, N, rowptr, bsum);
    hipLaunchKernelGGL(scan_top, dim3(1), dim3(512), 0, stream, bsum, nb256);
    hipLaunchKernelGGL(scan_add, dim3(nb256), dim3(256), 0, stream, rowptr, bsum, N);
    hipLaunchKernelGGL(fill_csr, dim3(eb256), dim3(256), 0, stream, ei, E, rowptr, csr);
    hipLaunchKernelGGL(gin_gather_kernel, dim3(nb4), dim3(256), 0, stream,
                       h0, rowptr, deg, csr, gin_W, gin_b, h1, N);
    for (int s = 0; s < STEPS; ++s) {
        hipLaunchKernelGGL(set2set_step_kernel, dim3(B_GRAPHS), dim3(256), 0, stream,
                           h1, W_ih, W_hh, b_ih, b_hh, startb, count,
                           q_star, hbuf, cbuf);
    }
    hipLaunchKernelGGL(head_kernel, dim3(B_GRAPHS), dim3(64), 0, stream,
                       q_star, lin1_W, lin1_b, lin2_W, lin2_b, out);
}

// Round 5
// 510.582 us; speedup vs baseline: 3.4344x; 1.1095x over previous
//
#include <hip/hip_runtime.h>
#include <math.h>

#define DIM 64
#define IN_DIM 25
#define B_GRAPHS 1024
#define STEPS 3
#define NRANGE 8          // dst-space partitions, mapped to XCDs via blockIdx%8
#define FILL_CHUNK 2048   // edges examined per block (8 grid-stride iters of 256)

__device__ __forceinline__ float wave_sum(float v) {
    #pragma unroll
    for (int o = 32; o > 0; o >>= 1) v += __shfl_xor(v, o, 64);
    return v;
}

// h0 = relu(x @ lin0_W + lin0_b). 4 nodes/block, lane = out channel.
__global__ void lin0_kernel(const float* __restrict__ x,
                            const float* __restrict__ W,
                            const float* __restrict__ b,
                            float* __restrict__ h0, int N) {
    int grp  = threadIdx.x >> 6;
    int lane = threadIdx.x & 63;
    int n = blockIdx.x * 4 + grp;
    if (n >= N) return;
    float acc = b[lane];
    const float* xr = x + (size_t)n * IN_DIM;
    #pragma unroll
    for (int k = 0; k < IN_DIM; ++k)
        acc += xr[k] * W[k * DIM + lane];
    h0[n * DIM + lane] = fmaxf(acc, 0.f);
}

// Combined: in-degree histogram (E threads) + per-graph start/count (N threads).
__global__ void hist_kernel(const int* __restrict__ ei, int E,
                            const int* __restrict__ batch, int N,
                            int* __restrict__ deg,
                            int* __restrict__ start, int* __restrict__ count) {
    int i = blockIdx.x * blockDim.x + threadIdx.x;
    if (i < E) atomicAdd(&deg[ei[E + i]], 1);
    if (i < N) {
        int b = batch[i];
        atomicAdd(&count[b], 1);
        if (i == 0 || batch[i - 1] != b) start[b] = i;
    }
}

// Block-level exclusive scan of deg -> rowptr; per-block totals -> bsum.
__global__ void scan_blocks(const int* __restrict__ deg, int N,
                            int* __restrict__ rowptr, int* __restrict__ bsum) {
    __shared__ int s[256];
    int i = blockIdx.x * 256 + threadIdx.x;
    int v = (i < N) ? deg[i] : 0;
    s[threadIdx.x] = v;
    __syncthreads();
    for (int o = 1; o < 256; o <<= 1) {
        int t = (threadIdx.x >= o) ? s[threadIdx.x - o] : 0;
        __syncthreads();
        s[threadIdx.x] += t;
        __syncthreads();
    }
    if (i < N) rowptr[i] = s[threadIdx.x] - v;   // exclusive
    if (threadIdx.x == 255) bsum[blockIdx.x] = s[255];
}

// Exclusive scan of the (<512) block totals, in place.
__global__ void scan_top(int* __restrict__ bsum, int nb) {
    __shared__ int s[512];
    int v = (threadIdx.x < nb) ? bsum[threadIdx.x] : 0;
    s[threadIdx.x] = v;
    __syncthreads();
    for (int o = 1; o < 512; o <<= 1) {
        int t = (threadIdx.x >= o) ? s[threadIdx.x - o] : 0;
        __syncthreads();
        s[threadIdx.x] += t;
        __syncthreads();
    }
    if (threadIdx.x < nb) bsum[threadIdx.x] = s[threadIdx.x] - v;
}

__global__ void scan_add(int* __restrict__ rowptr, const int* __restrict__ bsum, int N) {
    int i = blockIdx.x * 256 + threadIdx.x;
    if (i < N) rowptr[i] += bsum[blockIdx.x];
}

// Fill CSR, XCD-partitioned: block handles edge chunk (blockIdx>>3), but only
// edges whose dst falls in range (blockIdx&7). Under round-robin block->XCD
// dispatch each rowptr/csr slice is touched by ONE XCD -> L2-coalesced writes
// (fixes the 105MB line-thrash WRITE_SIZE). Correct under any placement.
__global__ void fill_csr(const int* __restrict__ ei, int E, int npr,
                         int* __restrict__ rowptr, int* __restrict__ csr) {
    int range = blockIdx.x & (NRANGE - 1);
    int chunk = blockIdx.x >> 3;
    int lo = range * npr;
    int hi = lo + npr;
    int e0 = chunk * FILL_CHUNK;
    int e1 = min(E, e0 + FILL_CHUNK);
    for (int e = e0 + threadIdx.x; e < e1; e += 256) {
        int dst = ei[E + e];
        if (dst >= lo && dst < hi) {
            int src = ei[e];
            int pos = atomicAdd(&rowptr[dst], 1);
            csr[pos] = src;
        }
    }
}

// Fused neighbor-sum + GIN matmul. One wave per node (lane = channel).
// 8-way unrolled gather -> 8 outstanding loads per wave.
__global__ void gin_gather_kernel(const float* __restrict__ h0,
                                  const int* __restrict__ rowptr,  // inclusive
                                  const int* __restrict__ deg,
                                  const int* __restrict__ csr,
                                  const float* __restrict__ W,
                                  const float* __restrict__ bias,
                                  float* __restrict__ h1, int N) {
    int grp  = threadIdx.x >> 6;
    int lane = threadIdx.x & 63;
    int n = blockIdx.x * 4 + grp;
    __shared__ float s[4][DIM];
    if (n < N) {
        float a0 = h0[(size_t)n * DIM + lane];
        float a1 = 0.f, a2 = 0.f, a3 = 0.f, a4 = 0.f, a5 = 0.f, a6 = 0.f, a7 = 0.f;
        int end = rowptr[n];
        int d   = deg[n];
        for (int base = end - d; base < end; base += 64) {
            int idx = (base + lane < end) ? csr[base + lane] : 0;
            int m = end - base; if (m > 64) m = 64;
            int j = 0;
            for (; j + 8 <= m; j += 8) {
                int s0 = __shfl(idx, j + 0, 64);
                int s1 = __shfl(idx, j + 1, 64);
                int s2 = __shfl(idx, j + 2, 64);
                int s3 = __shfl(idx, j + 3, 64);
                int s4 = __shfl(idx, j + 4, 64);
                int s5 = __shfl(idx, j + 5, 64);
                int s6 = __shfl(idx, j + 6, 64);
                int s7 = __shfl(idx, j + 7, 64);
                float v0 = h0[(size_t)s0 * DIM + lane];
                float v1 = h0[(size_t)s1 * DIM + lane];
                float v2 = h0[(size_t)s2 * DIM + lane];
                float v3 = h0[(size_t)s3 * DIM + lane];
                float v4 = h0[(size_t)s4 * DIM + lane];
                float v5 = h0[(size_t)s5 * DIM + lane];
                float v6 = h0[(size_t)s6 * DIM + lane];
                float v7 = h0[(size_t)s7 * DIM + lane];
                a0 += v0; a1 += v1; a2 += v2; a3 += v3;
                a4 += v4; a5 += v5; a6 += v6; a7 += v7;
            }
            for (; j < m; ++j) {
                int sj = __shfl(idx, j, 64);
                a0 += h0[(size_t)sj * DIM + lane];
            }
        }
        s[grp][lane] = ((a0 + a1) + (a2 + a3)) + ((a4 + a5) + (a6 + a7));
    }
    __syncthreads();
    if (n >= N) return;
    float acc = bias[lane];
    #pragma unroll 8
    for (int k = 0; k < DIM; ++k)
        acc += s[grp][k] * W[k * DIM + lane];
    h1[(size_t)n * DIM + lane] = fmaxf(acc, 0.f);
}

// One block (256 thr) per graph: LSTM cell + softmax attention, fused.
__global__ void set2set_step_kernel(const float* __restrict__ h1,
                                    const float* __restrict__ W_ih,
                                    const float* __restrict__ W_hh,
                                    const float* __restrict__ b_ih,
                                    const float* __restrict__ b_hh,
                                    const int* __restrict__ start,
                                    const int* __restrict__ count,
                                    float* __restrict__ q_star,
                                    float* __restrict__ h,
                                    float* __restrict__ c) {
    int b   = blockIdx.x;
    int tid = threadIdx.x;
    __shared__ __align__(16) float qs[2 * DIM];
    __shared__ __align__(16) float hs[DIM];
    __shared__ __align__(16) float q[DIM];
    __shared__ float gates[4 * DIM];
    __shared__ float smax[4];
    __shared__ float sden[16];
    __shared__ __align__(16) float4 sr[16][16];   // [grp*4+jslot][sub]

    // ---- LSTM ----
    if (tid < 2 * DIM)      qs[tid] = q_star[b * 2 * DIM + tid];
    else if (tid < 3 * DIM) hs[tid - 2 * DIM] = h[b * DIM + (tid - 2 * DIM)];
    __syncthreads();
    {
        float acc = b_ih[tid] + b_hh[tid];
        const float4* wi4 = (const float4*)(W_ih + (size_t)tid * 2 * DIM);
        const float4* qs4 = (const float4*)qs;
        #pragma unroll
        for (int k = 0; k < 2 * DIM / 4; ++k) {
            float4 w = wi4[k], v = qs4[k];
            acc += w.x * v.x + w.y * v.y + w.z * v.z + w.w * v.w;
        }
        const float4* wh4 = (const float4*)(W_hh + (size_t)tid * DIM);
        const float4* hs4 = (const float4*)hs;
        #pragma unroll
        for (int k = 0; k < DIM / 4; ++k) {
            float4 w = wh4[k], v = hs4[k];
            acc += w.x * v.x + w.y * v.y + w.z * v.z + w.w * v.w;
        }
        gates[tid] = acc;
    }
    __syncthreads();
    if (tid < DIM) {
        float ig = gates[tid];
        float fg = gates[DIM + tid];
        float gg = gates[2 * DIM + tid];
        float og = gates[3 * DIM + tid];
        float si = 1.f / (1.f + __expf(-ig));
        float sf = 1.f / (1.f + __expf(-fg));
        float so = 1.f / (1.f + __expf(-og));
        float cn = sf * c[b * DIM + tid] + si * tanhf(gg);
        float hn = so * tanhf(cn);
        c[b * DIM + tid] = cn;
        h[b * DIM + tid] = hn;
        q_star[b * 2 * DIM + tid] = hn;
        q[tid] = hn;
    }
    __syncthreads();

    // ---- attention: 4 nodes/wave, 16 lanes/node, float4 loads ----
    int lane  = tid & 63;
    int grp   = tid >> 6;
    int sub   = lane & 15;
    int jslot = lane >> 4;
    int st = start[b], cnt = count[b];
    const float4 q4 = *(const float4*)(&q[4 * sub]);

    float gmax = -INFINITY;
    for (int i = grp * 4 + jslot; i < cnt; i += 16) {
        const float4 v = *(const float4*)(h1 + (size_t)(st + i) * DIM + 4 * sub);
        float p = v.x * q4.x + v.y * q4.y + v.z * q4.z + v.w * q4.w;
        p += __shfl_xor(p, 1, 64);
        p += __shfl_xor(p, 2, 64);
        p += __shfl_xor(p, 4, 64);
        p += __shfl_xor(p, 8, 64);
        gmax = fmaxf(gmax, p);
    }
    gmax = fmaxf(gmax, __shfl_xor(gmax, 16, 64));
    gmax = fmaxf(gmax, __shfl_xor(gmax, 32, 64));
    if (lane == 0) smax[grp] = gmax;
    __syncthreads();
    float m = fmaxf(fmaxf(smax[0], smax[1]), fmaxf(smax[2], smax[3]));

    float4 racc = {0.f, 0.f, 0.f, 0.f};
    float den = 0.f;
    for (int i = grp * 4 + jslot; i < cnt; i += 16) {
        const float4 v = *(const float4*)(h1 + (size_t)(st + i) * DIM + 4 * sub);
        float p = v.x * q4.x + v.y * q4.y + v.z * q4.z + v.w * q4.w;
        p += __shfl_xor(p, 1, 64);
        p += __shfl_xor(p, 2, 64);
        p += __shfl_xor(p, 4, 64);
        p += __shfl_xor(p, 8, 64);
        float w = __expf(p - m);
        if (sub == 0) den += w;
        racc.x += w * v.x; racc.y += w * v.y; racc.z += w * v.z; racc.w += w * v.w;
    }
    sr[grp * 4 + jslot][sub] = racc;
    if (sub == 0) sden[grp * 4 + jslot] = den;
    __syncthreads();
    if (tid < DIM) {
        float tot = 0.f;
        #pragma unroll
        for (int row = 0; row < 16; ++row) {
            const float* base = (const float*)&sr[row][tid >> 2];
            tot += base[tid & 3];
        }
        float dt = 0.f;
        #pragma unroll
        for (int row = 0; row < 16; ++row) dt += sden[row];
        if (dt == 0.f) dt = 1.f;
        q_star[b * 2 * DIM + DIM + tid] = tot / dt;
    }
}

// out[b] = relu(q_star @ lin1_W + lin1_b) @ lin2_W + lin2_b. One wave per graph.
__global__ void head_kernel(const float* __restrict__ q_star,
                            const float* __restrict__ lin1_W,
                            const float* __restrict__ lin1_b,
                            const float* __restrict__ lin2_W,
                            const float* __restrict__ lin2_b,
                            float* __restrict__ out) {
    int b = blockIdx.x;
    int d = threadIdx.x;  // block of 64
    __shared__ float qs[2 * DIM];
    qs[d]       = q_star[b * 2 * DIM + d];
    qs[DIM + d] = q_star[b * 2 * DIM + DIM + d];
    __syncthreads();
    float acc = lin1_b[d];
    #pragma unroll 8
    for (int k = 0; k < 2 * DIM; ++k) acc += qs[k] * lin1_W[k * DIM + d];
    acc = fmaxf(acc, 0.f);
    float v = acc * lin2_W[d];
    v = wave_sum(v);
    if (d == 0) out[b] = v + lin2_b[0];
}

extern "C" void kernel_launch(void* const* d_in, const int* in_sizes, int n_in,
                              void* d_out, int out_size, void* d_ws, size_t ws_size,
                              hipStream_t stream) {
    const float* x      = (const float*)d_in[0];
    const int*   ei     = (const int*)d_in[1];
    const int*   batch  = (const int*)d_in[2];
    const float* lin0_W = (const float*)d_in[3];
    const float* lin0_b = (const float*)d_in[4];
    const float* gin_W  = (const float*)d_in[5];
    const float* gin_b  = (const float*)d_in[6];
    const float* W_ih   = (const float*)d_in[7];
    const float* W_hh   = (const float*)d_in[8];
    const float* b_ih   = (const float*)d_in[9];
    const float* b_hh   = (const float*)d_in[10];
    const float* lin1_W = (const float*)d_in[11];
    const float* lin1_b = (const float*)d_in[12];
    const float* lin2_W = (const float*)d_in[13];
    const float* lin2_b = (const float*)d_in[14];
    float* out = (float*)d_out;

    const int N = in_sizes[2];        // 100000 nodes
    const int E = in_sizes[1] / 2;    // 1600000 edges

    char* ws = (char*)d_ws;
    size_t off = 0;
    auto take = [&](size_t bytes) -> char* {
        char* p = ws + off;
        off += (bytes + 255) & ~(size_t)255;
        return p;
    };
    float* h0     = (float*)take((size_t)N * DIM * 4);
    float* h1     = (float*)take((size_t)N * DIM * 4);
    // ---- zeroed region start (one contiguous memset) ----
    float* q_star = (float*)take((size_t)B_GRAPHS * 2 * DIM * 4);
    float* hbuf   = (float*)take((size_t)B_GRAPHS * DIM * 4);
    float* cbuf   = (float*)take((size_t)B_GRAPHS * DIM * 4);
    int*   count  = (int*)take((size_t)B_GRAPHS * 4);
    int*   deg    = (int*)take((size_t)N * 4);
    // ---- zeroed region end ----
    int*   startb = (int*)take((size_t)B_GRAPHS * 4);
    int*   rowptr = (int*)take((size_t)N * 4);
    int*   bsum   = (int*)take((size_t)512 * 4);
    int*   csr    = (int*)take((size_t)E * 4);

    size_t zero_bytes = (size_t)((char*)startb - (char*)q_star);
    hipMemsetAsync(q_star, 0, zero_bytes, stream);

    int nb4   = (N + 3) / 4;
    int nb256 = (N + 255) / 256;
    int eb256 = (E + 255) / 256;
    int npr   = (N + NRANGE - 1) / NRANGE;           // nodes per dst-range
    int fill_blocks = ((E + FILL_CHUNK - 1) / FILL_CHUNK) * NRANGE;

    hipLaunchKernelGGL(lin0_kernel, dim3(nb4), dim3(256), 0, stream,
                       x, lin0_W, lin0_b, h0, N);
    hipLaunchKernelGGL(hist_kernel, dim3(eb256), dim3(256), 0, stream,
                       ei, E, batch, N, deg, startb, count);
    hipLaunchKernelGGL(scan_blocks, dim3(nb256), dim3(256), 0, stream,
                       deg, N, rowptr, bsum);
    hipLaunchKernelGGL(scan_top, dim3(1), dim3(512), 0, stream, bsum, nb256);
    hipLaunchKernelGGL(scan_add, dim3(nb256), dim3(256), 0, stream, rowptr, bsum, N);
    hipLaunchKernelGGL(fill_csr, dim3(fill_blocks), dim3(256), 0, stream,
                       ei, E, npr, rowptr, csr);
    hipLaunchKernelGGL(gin_gather_kernel, dim3(nb4), dim3(256), 0, stream,
                       h0, rowptr, deg, csr, gin_W, gin_b, h1, N);
    for (int s = 0; s < STEPS; ++s) {
        hipLaunchKernelGGL(set2set_step_kernel, dim3(B_GRAPHS), dim3(256), 0, stream,
                           h1, W_ih, W_hh, b_ih, b_hh, startb, count,
                           q_star, hbuf, cbuf);
    }
    hipLaunchKernelGGL(head_kernel, dim3(B_GRAPHS), dim3(64), 0, stream,
                       q_star, lin1_W, lin1_b, lin2_W, lin2_b, out);
}

// Round 6
// 509.607 us; speedup vs baseline: 3.4410x; 1.0019x over previous
//
#include <hip/hip_runtime.h>
#include <math.h>

#define DIM 64
#define IN_DIM 25
#define B_GRAPHS 1024
#define STEPS 3
#define NRANGE 8          // dst-space partitions, mapped to XCDs via blockIdx%8
#define FILL_CHUNK 2048   // edges examined per fill block
#define LDSCAP 128        // h1 rows staged in LDS per graph (32 KB); global fallback past this

__device__ __forceinline__ float wave_sum(float v) {
    #pragma unroll
    for (int o = 32; o > 0; o >>= 1) v += __shfl_xor(v, o, 64);
    return v;
}

// h0 = relu(x @ lin0_W + lin0_b). 4 nodes/block, lane = out channel.
__global__ void lin0_kernel(const float* __restrict__ x,
                            const float* __restrict__ W,
                            const float* __restrict__ b,
                            float* __restrict__ h0, int N) {
    int grp  = threadIdx.x >> 6;
    int lane = threadIdx.x & 63;
    int n = blockIdx.x * 4 + grp;
    if (n >= N) return;
    float acc = b[lane];
    const float* xr = x + (size_t)n * IN_DIM;
    #pragma unroll
    for (int k = 0; k < IN_DIM; ++k)
        acc += xr[k] * W[k * DIM + lane];
    h0[n * DIM + lane] = fmaxf(acc, 0.f);
}

// Combined: in-degree histogram (E threads) + per-graph start/count (N threads).
__global__ void hist_kernel(const int* __restrict__ ei, int E,
                            const int* __restrict__ batch, int N,
                            int* __restrict__ deg,
                            int* __restrict__ start, int* __restrict__ count) {
    int i = blockIdx.x * blockDim.x + threadIdx.x;
    if (i < E) atomicAdd(&deg[ei[E + i]], 1);
    if (i < N) {
        int b = batch[i];
        atomicAdd(&count[b], 1);
        if (i == 0 || batch[i - 1] != b) start[b] = i;
    }
}

// Block-level exclusive scan of deg -> rowptr; per-block totals -> bsum.
__global__ void scan_blocks(const int* __restrict__ deg, int N,
                            int* __restrict__ rowptr, int* __restrict__ bsum) {
    __shared__ int s[256];
    int i = blockIdx.x * 256 + threadIdx.x;
    int v = (i < N) ? deg[i] : 0;
    s[threadIdx.x] = v;
    __syncthreads();
    for (int o = 1; o < 256; o <<= 1) {
        int t = (threadIdx.x >= o) ? s[threadIdx.x - o] : 0;
        __syncthreads();
        s[threadIdx.x] += t;
        __syncthreads();
    }
    if (i < N) rowptr[i] = s[threadIdx.x] - v;   // exclusive
    if (threadIdx.x == 255) bsum[blockIdx.x] = s[255];
}

// Exclusive scan of the (<512) block totals, in place.
__global__ void scan_top(int* __restrict__ bsum, int nb) {
    __shared__ int s[512];
    int v = (threadIdx.x < nb) ? bsum[threadIdx.x] : 0;
    s[threadIdx.x] = v;
    __syncthreads();
    for (int o = 1; o < 512; o <<= 1) {
        int t = (threadIdx.x >= o) ? s[threadIdx.x - o] : 0;
        __syncthreads();
        s[threadIdx.x] += t;
        __syncthreads();
    }
    if (threadIdx.x < nb) bsum[threadIdx.x] = s[threadIdx.x] - v;
}

__global__ void scan_add(int* __restrict__ rowptr, const int* __restrict__ bsum, int N) {
    int i = blockIdx.x * 256 + threadIdx.x;
    if (i < N) rowptr[i] += bsum[blockIdx.x];
}

// Fill CSR, XCD-partitioned (see R4): each rowptr/csr slice touched by one XCD.
__global__ void fill_csr(const int* __restrict__ ei, int E, int npr,
                         int* __restrict__ rowptr, int* __restrict__ csr) {
    int range = blockIdx.x & (NRANGE - 1);
    int chunk = blockIdx.x >> 3;
    int lo = range * npr;
    int hi = lo + npr;
    int e0 = chunk * FILL_CHUNK;
    int e1 = min(E, e0 + FILL_CHUNK);
    for (int e = e0 + threadIdx.x; e < e1; e += 256) {
        int dst = ei[E + e];
        if (dst >= lo && dst < hi) {
            int src = ei[e];
            int pos = atomicAdd(&rowptr[dst], 1);
            csr[pos] = src;
        }
    }
}

// Fused neighbor-sum + GIN matmul. One wave per node.
// Gather layout: sub=lane&15 (channel group, float4), jslot=lane>>4 (4 neighbor
// slots) -> one float4 load instr fetches 4 neighbor rows; 16 loads in flight.
__global__ void gin_gather_kernel(const float* __restrict__ h0,
                                  const int* __restrict__ rowptr,  // inclusive
                                  const int* __restrict__ deg,
                                  const int* __restrict__ csr,
                                  const float* __restrict__ W,
                                  const float* __restrict__ bias,
                                  float* __restrict__ h1, int N) {
    int grp   = threadIdx.x >> 6;
    int lane  = threadIdx.x & 63;
    int sub   = lane & 15;
    int jslot = lane >> 4;
    int n = blockIdx.x * 4 + grp;
    __shared__ __align__(16) float s[4][DIM];
    if (n < N) {
        float4 a0 = {0.f, 0.f, 0.f, 0.f};
        float4 a1 = {0.f, 0.f, 0.f, 0.f};
        int end = rowptr[n];
        int d   = deg[n];
        for (int base = end - d; base < end; base += 64) {
            int rem = end - base;
            int m = rem < 64 ? rem : 64;
            int idx = (base + lane < end) ? csr[base + lane] : 0;
            int j = 0;
            for (; j + 16 <= m; j += 16) {
                int s0 = __shfl(idx, j + jslot, 64);
                int s1 = __shfl(idx, j + 4 + jslot, 64);
                int s2 = __shfl(idx, j + 8 + jslot, 64);
                int s3 = __shfl(idx, j + 12 + jslot, 64);
                float4 v0 = *(const float4*)(h0 + (size_t)s0 * DIM + 4 * sub);
                float4 v1 = *(const float4*)(h0 + (size_t)s1 * DIM + 4 * sub);
                float4 v2 = *(const float4*)(h0 + (size_t)s2 * DIM + 4 * sub);
                float4 v3 = *(const float4*)(h0 + (size_t)s3 * DIM + 4 * sub);
                a0.x += v0.x; a0.y += v0.y; a0.z += v0.z; a0.w += v0.w;
                a1.x += v1.x; a1.y += v1.y; a1.z += v1.z; a1.w += v1.w;
                a0.x += v2.x; a0.y += v2.y; a0.z += v2.z; a0.w += v2.w;
                a1.x += v3.x; a1.y += v3.y; a1.z += v3.z; a1.w += v3.w;
            }
            for (; j < m; j += 4) {
                int jj = j + jslot;
                int sj = __shfl(idx, jj < m ? jj : 0, 64);
                if (jj < m) {
                    float4 v = *(const float4*)(h0 + (size_t)sj * DIM + 4 * sub);
                    a0.x += v.x; a0.y += v.y; a0.z += v.z; a0.w += v.w;
                }
            }
        }
        float4 a;
        a.x = a0.x + a1.x; a.y = a0.y + a1.y; a.z = a0.z + a1.z; a.w = a0.w + a1.w;
        // reduce across the 4 jslots (lane bits 4,5)
        a.x += __shfl_xor(a.x, 16, 64); a.y += __shfl_xor(a.y, 16, 64);
        a.z += __shfl_xor(a.z, 16, 64); a.w += __shfl_xor(a.w, 16, 64);
        a.x += __shfl_xor(a.x, 32, 64); a.y += __shfl_xor(a.y, 32, 64);
        a.z += __shfl_xor(a.z, 32, 64); a.w += __shfl_xor(a.w, 32, 64);
        if (jslot == 0) {
            const float4 self = *(const float4*)(h0 + (size_t)n * DIM + 4 * sub);
            a.x += self.x; a.y += self.y; a.z += self.z; a.w += self.w;
            *(float4*)(&s[grp][4 * sub]) = a;
        }
    }
    __syncthreads();
    if (n >= N) return;
    float acc = bias[lane];
    #pragma unroll 8
    for (int k = 0; k < DIM; ++k)
        acc += s[grp][k] * W[k * DIM + lane];
    h1[(size_t)n * DIM + lane] = fmaxf(acc, 0.f);
}

// Entire Set2Set (3 LSTM+attention steps) + output head, one block per graph.
// h1 slice staged in LDS once (<=LDSCAP rows; global fallback past that).
__global__ __launch_bounds__(256)
void set2set_fused_kernel(const float* __restrict__ h1,
                          const float* __restrict__ W_ih,
                          const float* __restrict__ W_hh,
                          const float* __restrict__ b_ih,
                          const float* __restrict__ b_hh,
                          const int* __restrict__ start,
                          const int* __restrict__ count,
                          const float* __restrict__ lin1_W,
                          const float* __restrict__ lin1_b,
                          const float* __restrict__ lin2_W,
                          const float* __restrict__ lin2_b,
                          float* __restrict__ out) {
    int b   = blockIdx.x;
    int tid = threadIdx.x;
    __shared__ __align__(16) float sh1[LDSCAP * DIM];      // 32 KB
    __shared__ __align__(16) float hs[DIM];                // h (== q_star[0:64])
    __shared__ __align__(16) float cs[DIM];
    __shared__ __align__(16) float rs[DIM];                // r (== q_star[64:128])
    __shared__ float gates[4 * DIM];
    __shared__ float smax[4];
    __shared__ float sden[16];
    __shared__ __align__(16) float4 sr[16][16];

    int st = start[b], cnt = count[b];
    int stage = cnt < LDSCAP ? cnt : LDSCAP;

    // stage h1 slice (contiguous, float4-coalesced)
    {
        const float4* src = (const float4*)(h1 + (size_t)st * DIM);
        float4* dst = (float4*)sh1;
        for (int f = tid; f < stage * (DIM / 4); f += 256) dst[f] = src[f];
    }
    if (tid < DIM) { hs[tid] = 0.f; cs[tid] = 0.f; rs[tid] = 0.f; }
    __syncthreads();

    int lane  = tid & 63;
    int grp   = tid >> 6;
    int sub   = lane & 15;
    int jslot = lane >> 4;

    for (int step = 0; step < STEPS; ++step) {
        // ---- gates = [hs,rs] @ W_ih^T + hs @ W_hh^T + b ----
        {
            float acc = b_ih[tid] + b_hh[tid];
            const float4* wi = (const float4*)(W_ih + (size_t)tid * 2 * DIM);
            const float4* h4 = (const float4*)hs;
            const float4* r4 = (const float4*)rs;
            #pragma unroll
            for (int k = 0; k < DIM / 4; ++k) {
                float4 w = wi[k], v = h4[k];
                acc += w.x * v.x + w.y * v.y + w.z * v.z + w.w * v.w;
            }
            #pragma unroll
            for (int k = 0; k < DIM / 4; ++k) {
                float4 w = wi[DIM / 4 + k], v = r4[k];
                acc += w.x * v.x + w.y * v.y + w.z * v.z + w.w * v.w;
            }
            const float4* wh = (const float4*)(W_hh + (size_t)tid * DIM);
            #pragma unroll
            for (int k = 0; k < DIM / 4; ++k) {
                float4 w = wh[k], v = h4[k];
                acc += w.x * v.x + w.y * v.y + w.z * v.z + w.w * v.w;
            }
            gates[tid] = acc;
        }
        __syncthreads();
        if (tid < DIM) {
            float ig = gates[tid];
            float fg = gates[DIM + tid];
            float gg = gates[2 * DIM + tid];
            float og = gates[3 * DIM + tid];
            float si = 1.f / (1.f + __expf(-ig));
            float sf = 1.f / (1.f + __expf(-fg));
            float so = 1.f / (1.f + __expf(-og));
            float cn = sf * cs[tid] + si * tanhf(gg);
            float hn = so * tanhf(cn);
            cs[tid] = cn;
            hs[tid] = hn;
        }
        __syncthreads();

        // ---- attention: q = hs; 4 nodes/wave, 16 lanes/node ----
        const float4 q4 = *(const float4*)(&hs[4 * sub]);

        float gmax = -INFINITY;
        for (int i = grp * 4 + jslot; i < cnt; i += 16) {
            const float4 v = (i < stage)
                ? *(const float4*)(sh1 + i * DIM + 4 * sub)
                : *(const float4*)(h1 + (size_t)(st + i) * DIM + 4 * sub);
            float p = v.x * q4.x + v.y * q4.y + v.z * q4.z + v.w * q4.w;
            p += __shfl_xor(p, 1, 64);
            p += __shfl_xor(p, 2, 64);
            p += __shfl_xor(p, 4, 64);
            p += __shfl_xor(p, 8, 64);
            gmax = fmaxf(gmax, p);
        }
        gmax = fmaxf(gmax, __shfl_xor(gmax, 16, 64));
        gmax = fmaxf(gmax, __shfl_xor(gmax, 32, 64));
        if (lane == 0) smax[grp] = gmax;
        __syncthreads();
        float m = fmaxf(fmaxf(smax[0], smax[1]), fmaxf(smax[2], smax[3]));

        float4 racc = {0.f, 0.f, 0.f, 0.f};
        float den = 0.f;
        for (int i = grp * 4 + jslot; i < cnt; i += 16) {
            const float4 v = (i < stage)
                ? *(const float4*)(sh1 + i * DIM + 4 * sub)
                : *(const float4*)(h1 + (size_t)(st + i) * DIM + 4 * sub);
            float p = v.x * q4.x + v.y * q4.y + v.z * q4.z + v.w * q4.w;
            p += __shfl_xor(p, 1, 64);
            p += __shfl_xor(p, 2, 64);
            p += __shfl_xor(p, 4, 64);
            p += __shfl_xor(p, 8, 64);
            float w = __expf(p - m);
            if (sub == 0) den += w;
            racc.x += w * v.x; racc.y += w * v.y; racc.z += w * v.z; racc.w += w * v.w;
        }
        sr[grp * 4 + jslot][sub] = racc;
        if (sub == 0) sden[grp * 4 + jslot] = den;
        __syncthreads();
        if (tid < DIM) {
            float tot = 0.f;
            #pragma unroll
            for (int row = 0; row < 16; ++row) {
                const float* base = (const float*)&sr[row][tid >> 2];
                tot += base[tid & 3];
            }
            float dt = 0.f;
            #pragma unroll
            for (int row = 0; row < 16; ++row) dt += sden[row];
            if (dt == 0.f) dt = 1.f;
            rs[tid] = tot / dt;
        }
        __syncthreads();
    }

    // ---- head: out[b] = relu([hs,rs] @ lin1_W + b1) @ lin2_W + b2 ----
    if (tid < DIM) {
        float acc = lin1_b[tid];
        #pragma unroll 8
        for (int k = 0; k < DIM; ++k) acc += hs[k] * lin1_W[k * DIM + tid];
        #pragma unroll 8
        for (int k = 0; k < DIM; ++k) acc += rs[k] * lin1_W[(DIM + k) * DIM + tid];
        acc = fmaxf(acc, 0.f);
        float v = acc * lin2_W[tid];
        v = wave_sum(v);
        if (tid == 0) out[b] = v + lin2_b[0];
    }
}

extern "C" void kernel_launch(void* const* d_in, const int* in_sizes, int n_in,
                              void* d_out, int out_size, void* d_ws, size_t ws_size,
                              hipStream_t stream) {
    const float* x      = (const float*)d_in[0];
    const int*   ei     = (const int*)d_in[1];
    const int*   batch  = (const int*)d_in[2];
    const float* lin0_W = (const float*)d_in[3];
    const float* lin0_b = (const float*)d_in[4];
    const float* gin_W  = (const float*)d_in[5];
    const float* gin_b  = (const float*)d_in[6];
    const float* W_ih   = (const float*)d_in[7];
    const float* W_hh   = (const float*)d_in[8];
    const float* b_ih   = (const float*)d_in[9];
    const float* b_hh   = (const float*)d_in[10];
    const float* lin1_W = (const float*)d_in[11];
    const float* lin1_b = (const float*)d_in[12];
    const float* lin2_W = (const float*)d_in[13];
    const float* lin2_b = (const float*)d_in[14];
    float* out = (float*)d_out;

    const int N = in_sizes[2];        // 100000 nodes
    const int E = in_sizes[1] / 2;    // 1600000 edges

    char* ws = (char*)d_ws;
    size_t off = 0;
    auto take = [&](size_t bytes) -> char* {
        char* p = ws + off;
        off += (bytes + 255) & ~(size_t)255;
        return p;
    };
    float* h0     = (float*)take((size_t)N * DIM * 4);
    float* h1     = (float*)take((size_t)N * DIM * 4);
    // ---- zeroed region start (one contiguous memset) ----
    int*   count  = (int*)take((size_t)B_GRAPHS * 4);
    int*   deg    = (int*)take((size_t)N * 4);
    // ---- zeroed region end ----
    int*   startb = (int*)take((size_t)B_GRAPHS * 4);
    int*   rowptr = (int*)take((size_t)N * 4);
    int*   bsum   = (int*)take((size_t)512 * 4);
    int*   csr    = (int*)take((size_t)E * 4);

    size_t zero_bytes = (size_t)((char*)startb - (char*)count);
    hipMemsetAsync(count, 0, zero_bytes, stream);

    int nb4   = (N + 3) / 4;
    int nb256 = (N + 255) / 256;
    int eb256 = (E + 255) / 256;
    int npr   = (N + NRANGE - 1) / NRANGE;
    int fill_blocks = ((E + FILL_CHUNK - 1) / FILL_CHUNK) * NRANGE;

    hipLaunchKernelGGL(lin0_kernel, dim3(nb4), dim3(256), 0, stream,
                       x, lin0_W, lin0_b, h0, N);
    hipLaunchKernelGGL(hist_kernel, dim3(eb256), dim3(256), 0, stream,
                       ei, E, batch, N, deg, startb, count);
    hipLaunchKernelGGL(scan_blocks, dim3(nb256), dim3(256), 0, stream,
                       deg, N, rowptr, bsum);
    hipLaunchKernelGGL(scan_top, dim3(1), dim3(512), 0, stream, bsum, nb256);
    hipLaunchKernelGGL(scan_add, dim3(nb256), dim3(256), 0, stream, rowptr, bsum, N);
    hipLaunchKernelGGL(fill_csr, dim3(fill_blocks), dim3(256), 0, stream,
                       ei, E, npr, rowptr, csr);
    hipLaunchKernelGGL(gin_gather_kernel, dim3(nb4), dim3(256), 0, stream,
                       h0, rowptr, deg, csr, gin_W, gin_b, h1, N);
    hipLaunchKernelGGL(set2set_fused_kernel, dim3(B_GRAPHS), dim3(256), 0, stream,
                       h1, W_ih, W_hh, b_ih, b_hh, startb, count,
                       lin1_W, lin1_b, lin2_W, lin2_b, out);
}